// Round 6
// baseline (249.494 us; speedup 1.0000x reference)
//
#include <hip/hip_runtime.h>
#include <hip/hip_bf16.h>

#define D_MODEL 4096
#define NTOK    8192   // B*S = 4*2048
#define SEQ     2048
#define RS      264    // LDS row stride in shorts (528 B = 33*16): +16B pad -> conflict-free b128

typedef short bf16x8 __attribute__((ext_vector_type(8)));  // 8 bf16 in 4 VGPRs
typedef float f32x4  __attribute__((ext_vector_type(4)));

typedef const __attribute__((address_space(1))) char* gas1_t;
typedef __attribute__((address_space(3))) char* las3_t;

__device__ inline void async16(const void* g, void* l) {
  // direct global->LDS DMA, 16 B/lane; LDS dest = wave-uniform base + lane*16
  __builtin_amdgcn_global_load_lds((gas1_t)g, (las3_t)l, 16, 0, 0);
}

__device__ inline short f2bf(float x) {
  __hip_bfloat16 h = __float2bfloat16(x);
  return *reinterpret_cast<short*>(&h);
}
__device__ inline float bf2f(const void* p, size_t i) {
  return __bfloat162float(((const __hip_bfloat16*)p)[i]);
}

// ---------------------------------------------------------------------------
// Kernel 0: dtype sniffing (confirmed: hidden=bf16, weights=f32; kept for
// robustness). flag=1 -> read as bf16[], flag=0 -> read as float[].
// ---------------------------------------------------------------------------
__global__ __launch_bounds__(320) void sniff_k(const void* hid, const void* wf,
                                               const void* w1, const void* w2,
                                               const void* b1, const void* b2,
                                               const void* lam,
                                               int* flags, float* scal) {
  int wv = threadIdx.x >> 6, lane = threadIdx.x & 63;
  const unsigned short* p = nullptr;
  int n = 0;
  switch (wv) {
    case 0: p = (const unsigned short*)hid; n = NTOK * D_MODEL; break;
    case 1: p = (const unsigned short*)wf;  n = 16 * D_MODEL;   break;
    case 2: p = (const unsigned short*)w1;  n = 64 * 4112;      break;
    case 3: p = (const unsigned short*)w2;  n = 64;             break;
    case 4: p = (const unsigned short*)b1;  n = 64;             break;
  }
  int S = n / 2 < 64 ? n / 2 : 64;
  bool act = lane < S;
  unsigned short ve = 0, vo = 0;
  if (act) { ve = p[2 * lane]; vo = p[2 * lane + 1]; }
  int ee = (ve >> 7) & 0xFF, eo = (vo >> 7) & 0xFF;
  bool ve_band   = (ve == 0) || (ve == 0x8000) || (ee >= 96 && ee <= 141);
  bool vo_bandnz = (vo != 0) && (vo != 0x8000) && (eo >= 96 && eo <= 141);
  int zp = __popcll(__ballot(act && ve == 0 && vo == 0));
  int ob = __popcll(__ballot(act && ve == 0 && vo_bandnz));
  int eb = __popcll(__ballot(act && ve_band));
  if (lane == 0) {
    int f;
    if (zp == S) f = 1;
    else if (4 * ob >= 3 * S) f = 0;    // f32 storage of bf16-rounded values
    else if (4 * eb >= 3 * S) f = 1;    // true bf16
    else f = 0;                         // raw f32
    flags[wv] = f;
  }
  if (threadIdx.x == 0) {
    unsigned short l0 = *(const unsigned short*)lam;
    int le = (l0 >> 7) & 0xFF;
    if (l0 != 0 && l0 != 0x8000 && le >= 96 && le <= 141)
      scal[0] = __bfloat162float(*(const __hip_bfloat16*)lam);
    else
      scal[0] = *(const float*)lam;
    unsigned short c0 = *(const unsigned short*)b2;
    int ce = (c0 >> 7) & 0xFF;
    if (c0 == 0) scal[1] = 0.0f;
    else if (c0 != 0x8000 && ce >= 96 && ce <= 141)
      scal[1] = __bfloat162float(*(const __hip_bfloat16*)b2);
    else
      scal[1] = *(const float*)b2;
  }
}

// ---------------------------------------------------------------------------
// Kernel 1: fold W_fiber into W1 -> W1_eff[64][4096] bf16 (internal format).
// ---------------------------------------------------------------------------
__global__ __launch_bounds__(256) void fold_w1(const void* __restrict__ W1v,
                                               const void* __restrict__ Wfv,
                                               const int* __restrict__ flags,
                                               __hip_bfloat16* __restrict__ W1eff) {
  int n = blockIdx.x;  // 0..63
  int fw1 = flags[2], fwf = flags[1];
  __shared__ float w1b[16];
  if (threadIdx.x < 16) {
    size_t idx = (size_t)n * 4112 + 4096 + threadIdx.x;
    w1b[threadIdx.x] = fw1 ? bf2f(W1v, idx) : ((const float*)W1v)[idx];
  }
  __syncthreads();
  for (int k = threadIdx.x; k < D_MODEL; k += 256) {
    size_t idx = (size_t)n * 4112 + k;
    float v = fw1 ? bf2f(W1v, idx) : ((const float*)W1v)[idx];
#pragma unroll
    for (int f = 0; f < 16; ++f) {
      size_t wi = (size_t)f * D_MODEL + k;
      float wfv = fwf ? bf2f(Wfv, wi) : ((const float*)Wfv)[wi];
      v += w1b[f] * wfv;
    }
    W1eff[(size_t)n * D_MODEL + k] = __float2bfloat16(v);
  }
}

// ---------------------------------------------------------------------------
// Kernel 2: fully-fused GEMM (M-tile 32, full K) + epilogue -> delta[8192].
// Grid 256 (1 block/CU, LDS-bound), block 256 thr = 4 waves.
// Wave w: row-group rg=w&1 (16 rows), K-half kh=w>>1 (128 of each 256-chunk).
// Double-buffered async staging via global_load_lds (m97 path): each masked
// half-wave instruction DMAs one contiguous 512B row-chunk into a 528B-strided
// LDS row (bank-rotated -> conflict-free ds_read_b128). Pipeline per chunk:
// issue stage(c+1) [24 instr/wave], s_waitcnt vmcnt(24), raw s_barrier,
// compute(c), raw s_barrier. Loads for c+1 stay in flight across compute(c).
// MFMA 16x16x32 bf16: A[m=lane&15][k=8*(lane>>4)+j]; C: col(n)=lane&15,
// row(m)=(lane>>4)*4+reg (verified R3-R5). Epilogue: LDS K-half reduce,
// + b1, exact GELU, dot W2, + b2, softplus.
// ---------------------------------------------------------------------------
__global__ __launch_bounds__(256) void gemm_fused(const void* __restrict__ hid,
                                                  const short* __restrict__ B_,
                                                  const void* __restrict__ b1,
                                                  const void* __restrict__ w2,
                                                  const int* __restrict__ flags,
                                                  const float* __restrict__ scal,
                                                  float* __restrict__ delta) {
  __shared__ short As[2][32 * RS];   // 2 x 16.9 KB
  __shared__ short Bs[2][64 * RS];   // 2 x 33.8 KB
  int t = blockIdx.x;                // M-tile: rows [t*32, t*32+32)
  int tid = threadIdx.x;
  int w = tid >> 6, lane = tid & 63;
  int m = lane & 15, kg = lane >> 4;
  int kh = w >> 1, rg = w & 1;
  bool lo = lane < 32;
  int l5 = lane & 31;
  f32x4 acc[4];
#pragma unroll
  for (int g = 0; g < 4; ++g) acc[g] = (f32x4){0.f, 0.f, 0.f, 0.f};

  auto compute = [&](const short* Asc, const short* Bsc) {
#pragma unroll
    for (int j = 0; j < 4; ++j) {
      int ko = kh * 128 + j * 32 + kg * 8;
      bf16x8 a   = *(const bf16x8*)(Asc + (rg * 16 + m) * RS + ko);
      bf16x8 b0v = *(const bf16x8*)(Bsc + (m +  0) * RS + ko);
      bf16x8 b1v = *(const bf16x8*)(Bsc + (m + 16) * RS + ko);
      bf16x8 b2v = *(const bf16x8*)(Bsc + (m + 32) * RS + ko);
      bf16x8 b3v = *(const bf16x8*)(Bsc + (m + 48) * RS + ko);
      acc[0] = __builtin_amdgcn_mfma_f32_16x16x32_bf16(a, b0v, acc[0], 0, 0, 0);
      acc[1] = __builtin_amdgcn_mfma_f32_16x16x32_bf16(a, b1v, acc[1], 0, 0, 0);
      acc[2] = __builtin_amdgcn_mfma_f32_16x16x32_bf16(a, b2v, acc[2], 0, 0, 0);
      acc[3] = __builtin_amdgcn_mfma_f32_16x16x32_bf16(a, b3v, acc[3], 0, 0, 0);
    }
  };

  if (flags[0]) {  // hidden bf16 (confirmed path)
    const short* hidA = (const short*)hid;
    auto stage = [&](int c, int p) {  // 24 masked async instrs per wave
#pragma unroll
      for (int i = 0; i < 8; ++i) {   // A: 8 rows per wave
        int r = w * 8 + i;
        const short* gp = hidA + (size_t)(t * 32 + r) * D_MODEL + c * 256 + l5 * 8;
        if (lo) async16(gp, &As[p][r * RS]);
      }
#pragma unroll
      for (int i = 0; i < 16; ++i) {  // B: 16 rows per wave
        int r = w * 16 + i;
        const short* gp = B_ + (size_t)r * D_MODEL + c * 256 + l5 * 8;
        if (lo) async16(gp, &Bs[p][r * RS]);
      }
    };
    stage(0, 0);
#pragma unroll 1
    for (int c = 0; c < 15; ++c) {
      stage(c + 1, (c + 1) & 1);
      __builtin_amdgcn_s_waitcnt(0x4F78);  // vmcnt(24): stage(c) done, stage(c+1) in flight
      __builtin_amdgcn_s_barrier();
      compute(As[c & 1], Bs[c & 1]);
      __builtin_amdgcn_s_barrier();        // reads of buf(c&1) done before stage(c+2)
    }
    __builtin_amdgcn_s_waitcnt(0x0F70);    // vmcnt(0): stage(15) done
    __builtin_amdgcn_s_barrier();
    compute(As[1], Bs[1]);
  } else {         // f32 fallback: single-buffer, plain barriers
    const float* hidF = (const float*)hid;
#pragma unroll 1
    for (int c = 0; c < 16; ++c) {
#pragma unroll
      for (int i = 0; i < 16; ++i) {
        int r = w * 16 + i;
        const short* gp = B_ + (size_t)r * D_MODEL + c * 256 + l5 * 8;
        if (lo) async16(gp, &Bs[0][r * RS]);
      }
      for (int e = tid; e < 32 * 256; e += 256) {
        int r = e >> 8, k = e & 255;
        As[0][r * RS + k] = f2bf(hidF[(size_t)(t * 32 + r) * D_MODEL + c * 256 + k]);
      }
      __syncthreads();   // drains vmcnt + lgkmcnt
      compute(As[0], Bs[0]);
      __syncthreads();
    }
  }

  // ---- epilogue: K-half reduce in LDS (aliases As[0], disjoint from buf 1) ----
  float* red = (float*)&As[0][0];  // [2][32][64] f32 = 16 KB
#pragma unroll
  for (int g = 0; g < 4; ++g)
#pragma unroll
    for (int r = 0; r < 4; ++r)
      red[kh * 2048 + (rg * 16 + kg * 4 + r) * 64 + g * 16 + m] = acc[g][r];
  __syncthreads();
  int row = tid >> 3, cid = tid & 7;
  int fb1 = flags[4], fw2 = flags[3];
  float y = 0.f;
#pragma unroll
  for (int j = 0; j < 8; ++j) {
    int col = cid + 8 * j;
    float s = red[row * 64 + col] + red[2048 + row * 64 + col];
    s += fb1 ? bf2f(b1, col) : ((const float*)b1)[col];
    float gg = 0.5f * s * (1.0f + erff(s * 0.70710678118654752f));  // exact GELU
    y += gg * (fw2 ? bf2f(w2, col) : ((const float*)w2)[col]);
  }
#pragma unroll
  for (int off = 1; off <= 4; off <<= 1) y += __shfl_xor(y, off, 64);
  if (cid == 0) {
    float x = y + scal[1];  // + b2
    delta[t * 32 + row] = (x > 20.0f) ? x : log1pf(expf(x));  // softplus
  }
}

// ---------------------------------------------------------------------------
// Kernel 3: causal EMA, gate, field, mean. OUTPUT IS FLOAT32 (mixed tuple
// (bf16,bf16,f32) concatenated by harness -> numpy-promoted f32).
// ---------------------------------------------------------------------------
__global__ __launch_bounds__(256) void ema_out(const float* __restrict__ delta,
                                               const float* __restrict__ scal,
                                               float* __restrict__ out) {
  int b    = threadIdx.x >> 6;   // batch 0..3
  int lane = threadIdx.x & 63;
  const float alpha = 0.9f;
  float d[32];
  const float* dp = delta + b * SEQ + lane * 32;
  float beta = 0.f, lsum = 0.f;
#pragma unroll
  for (int i = 0; i < 32; ++i) {
    d[i] = dp[i];
    lsum += d[i];
    beta = alpha * beta + 0.1f * d[i];
  }
  float accA = 0.03433683820292512f;  // 0.9^32
  float accB = beta;
  for (int off = 1; off < 64; off <<= 1) {
    float uA = __shfl_up(accA, off, 64);
    float uB = __shfl_up(accB, off, 64);
    if (lane >= off) {
      accB = accB + accA * uB;  // cur o prev
      accA = accA * uA;
    }
  }
  float prev = __shfl_up(accB, 1, 64);
  float h = (lane == 0) ? 0.f : prev;  // carry-in state for this chunk
  float lam = scal[0];
#pragma unroll
  for (int i = 0; i < 32; ++i) {
    h = alpha * h + 0.1f * d[i];
    float gate = 1.0f / (1.0f + expf(lam * h));  // sigmoid(-lam*h)
    out[b * SEQ + lane * 32 + i]        = gate;
    out[NTOK + b * SEQ + lane * 32 + i] = h;
  }
#pragma unroll
  for (int off = 32; off >= 1; off >>= 1) lsum += __shfl_xor(lsum, off, 64);
  __shared__ float bs[4];
  if (lane == 0) bs[b] = lsum;
  __syncthreads();
  if (threadIdx.x == 0)
    out[2 * NTOK] = (bs[0] + bs[1] + bs[2] + bs[3]) * (1.0f / 8192.0f);
}

// ---------------------------------------------------------------------------
extern "C" void kernel_launch(void* const* d_in, const int* in_sizes, int n_in,
                              void* d_out, int out_size, void* d_ws, size_t ws_size,
                              hipStream_t stream) {
  const void* hidden = d_in[0];  // [4,2048,4096]
  const void* Wf     = d_in[1];  // [16,4096]
  const void* W1     = d_in[2];  // [64,4112]
  const void* b1     = d_in[3];  // [64]
  const void* W2     = d_in[4];  // [1,64]
  const void* b2     = d_in[5];  // [1]
  const void* lam    = d_in[6];  // [1]
  float* out = (float*)d_out;    // 16385 f32 (gate 8192 | field 8192 | mean 1)

  // ws: [0,32) flags, [32,64) scal, [64, +512K) W1eff bf16, then delta f32.
  char* ws = (char*)d_ws;
  int*   flags = (int*)ws;
  float* scal  = (float*)(ws + 32);
  __hip_bfloat16* W1eff = (__hip_bfloat16*)(ws + 64);
  float* delta = (float*)(ws + 64 + (size_t)64 * D_MODEL * 2);

  sniff_k<<<1, 320, 0, stream>>>(hidden, Wf, W1, W2, b1, b2, lam, flags, scal);
  fold_w1<<<64, 256, 0, stream>>>(W1, Wf, flags, W1eff);
  gemm_fused<<<256, 256, 0, stream>>>(hidden, (const short*)W1eff, b1, W2, flags, scal, delta);
  ema_out<<<1, 256, 0, stream>>>(delta, scal, out);
}